// Round 1
// baseline (438.453 us; speedup 1.0000x reference)
//
#include <hip/hip_runtime.h>

#define IN_F 8192
#define OUT_F 8192
#define NBATCH 16
#define KC 512      // K-chunk staged in LDS
#define NG 64       // scale groups along IN (group size 128)

// block = 256 threads = 4 waves; each wave owns 4 output rows; lanes split K.
// grid = OUT_F/16 = 512 blocks (2 per CU).
__global__ __launch_bounds__(256, 2)
void axcore_dsew_linear_kernel(const float* __restrict__ x,
                               const float* __restrict__ w,
                               const float* __restrict__ scale,
                               const float* __restrict__ bias,
                               float* __restrict__ out) {
    // x^T chunk, [b][k] layout: row stride KC floats. 16*512*4 = 32 KB.
    __shared__ __align__(16) float xlds[NBATCH * KC];

    const int t    = threadIdx.x;
    const int wv   = t >> 6;      // wave id 0..3
    const int lane = t & 63;
    const int o0   = blockIdx.x * 16 + wv * 4;  // first of this wave's 4 rows

    float acc[4][16];
#pragma unroll
    for (int r = 0; r < 4; ++r)
#pragma unroll
        for (int b = 0; b < NBATCH; ++b) acc[r][b] = 0.f;

    for (int kc = 0; kc < IN_F; kc += KC) {
        __syncthreads();
        // ---- stage x[0:16, kc:kc+KC] into LDS as [b][k] ----
        // thread t, pass p: fidx in [0, 2048) float4s; b = fidx/128, kq = fidx%128
        // global read: wave reads 1 KB contiguous within one x row (coalesced)
        // LDS write: word = b*KC + 4*kq -> lane-stride-4 pattern (conflict-free class)
#pragma unroll
        for (int p = 0; p < 8; ++p) {
            const int fidx = p * 256 + t;
            const int bb = fidx >> 7;
            const int kq = fidx & 127;
            const float4 v = *(const float4*)&x[bb * IN_F + kc + 4 * kq];
            *(float4*)&xlds[bb * KC + 4 * kq] = v;
        }
        __syncthreads();

        // ---- per-chunk scales: 4 groups (kc/128 .. +3) per row, one float4 ----
        float4 scq[4];
#pragma unroll
        for (int r = 0; r < 4; ++r)
            scq[r] = *(const float4*)&scale[(o0 + r) * NG + (kc >> 7)];

        // ---- two steps of 256 K each: lane handles k = s*256 + 4*lane .. +3 ----
#pragma unroll
        for (int s = 0; s < 2; ++s) {
            const int klocal = s * 256 + 4 * lane;
            const int kg = kc + klocal;

            float4 wq[4];
#pragma unroll
            for (int r = 0; r < 4; ++r)
                wq[r] = *(const float4*)&w[(size_t)(o0 + r) * IN_F + kg];

            // dequant: group = klocal/128 = 2*s + (lane>=32)
#pragma unroll
            for (int r = 0; r < 4; ++r) {
                float sr;
                if (s == 0) sr = (lane < 32) ? scq[r].x : scq[r].y;
                else        sr = (lane < 32) ? scq[r].z : scq[r].w;
                wq[r].x *= sr; wq[r].y *= sr; wq[r].z *= sr; wq[r].w *= sr;
            }

#pragma unroll
            for (int b = 0; b < NBATCH; ++b) {
                const float4 xv = *(const float4*)&xlds[b * KC + klocal];
#pragma unroll
                for (int r = 0; r < 4; ++r) {
                    acc[r][b] += wq[r].x * xv.x;
                    acc[r][b] += wq[r].y * xv.y;
                    acc[r][b] += wq[r].z * xv.z;
                    acc[r][b] += wq[r].w * xv.w;
                }
            }
        }
    }

    // ---- epilogue: butterfly-reduce each acc across the 64 lanes ----
#pragma unroll
    for (int r = 0; r < 4; ++r) {
        const int o = o0 + r;
        const float bs = bias[o];
#pragma unroll
        for (int b = 0; b < NBATCH; ++b) {
            float v = acc[r][b];
            v += __shfl_xor(v, 1);
            v += __shfl_xor(v, 2);
            v += __shfl_xor(v, 4);
            v += __shfl_xor(v, 8);
            v += __shfl_xor(v, 16);
            v += __shfl_xor(v, 32);
            if (lane == 0) out[b * OUT_F + o] = v + bs;
        }
    }
}

extern "C" void kernel_launch(void* const* d_in, const int* in_sizes, int n_in,
                              void* d_out, int out_size, void* d_ws, size_t ws_size,
                              hipStream_t stream) {
    const float* x    = (const float*)d_in[0];
    const float* w    = (const float*)d_in[1];
    const float* sc   = (const float*)d_in[2];
    const float* bias = (const float*)d_in[3];
    // d_in[4] = types: constant lookup in the reference, no float math -> unused
    float* out = (float*)d_out;

    dim3 grid(OUT_F / 16), block(256);
    hipLaunchKernelGGL(axcore_dsew_linear_kernel, grid, block, 0, stream,
                       x, w, sc, bias, out);
}